// Round 2
// baseline (1569.322 us; speedup 1.0000x reference)
//
#include <hip/hip_runtime.h>
#include <hip/hip_bf16.h>
#include <stdint.h>

// ---------------------------------------------------------------------------
// DQN hypergraph-conv pipeline, fp32 correctness-first baseline (round 2).
//
// Round-1 bug: B-tile staging loop ran 4 iterations instead of 8, leaving
// Bs[32..63][*] uninitialized -> 1e12 absmax. Fixed.
//
// DROP_VARIANT (jax.random.bernoulli(key(42), 0.5, (8192,128)) bit stream):
//  1: partitionable, SECOND output word
//  2: legacy path (split-iota halves)
//  3: partitionable, FIRST output word
//  4: partitionable, XOR of both words   <- matches jax/_src/prng.py
//     _threefry_random_bits_partitionable: bits1 ^ bits2 over counts
//     (hi=0, lo=flat_idx), key=(0,42). keep <=> MSB==0.
// ---------------------------------------------------------------------------

#define DROP_VARIANT 4

static constexpr int BM = 16;    // output rows per block
static constexpr int BK = 64;    // K tile
static constexpr int BN = 128;   // full output width (always 128 here)
static constexpr int AST = BM + 4;   // padded LDS stride (floats)
static constexpr int BST = BN + 4;

enum { EPI_NONE = 0, EPI_ROWSCALE = 1, EPI_LRELU_DROP = 2, EPI_LRELU2_FC = 3 };

__device__ __forceinline__ unsigned rotl32(unsigned x, int r) {
  return (x << r) | (x >> (32 - r));
}

// Threefry-2x32, 20 rounds, exactly as in jax/_src/prng.py lowering.
__device__ __forceinline__ uint2 threefry2x32(unsigned k0, unsigned k1,
                                              unsigned x0, unsigned x1) {
  unsigned ks[3] = {k0, k1, k0 ^ k1 ^ 0x1BD11BDAu};
  x0 += ks[0];
  x1 += ks[1];
  const int R0[4] = {13, 15, 26, 6};
  const int R1[4] = {17, 29, 16, 24};
#pragma unroll
  for (int i = 0; i < 5; ++i) {
#pragma unroll
    for (int j = 0; j < 4; ++j) {
      const int r = (i % 2 == 0) ? R0[j] : R1[j];
      x0 += x1;
      x1 = rotl32(x1, r);
      x1 ^= x0;
    }
    x0 += ks[(i + 1) % 3];
    x1 += ks[(i + 2) % 3] + (unsigned)(i + 1);
  }
  return make_uint2(x0, x1);
}

__device__ __forceinline__ float drop_scale(unsigned idx) {
#if DROP_VARIANT == 1
  const uint2 o = threefry2x32(0u, 42u, 0u, idx);
  const unsigned bits = o.y;
#elif DROP_VARIANT == 2
  const unsigned HALF = 524288u;  // (8192*128)/2
  const unsigned lo = (idx < HALF) ? idx : (idx - HALF);
  const uint2 o = threefry2x32(0u, 42u, lo, lo + HALF);
  const unsigned bits = (idx < HALF) ? o.x : o.y;
#elif DROP_VARIANT == 3
  const uint2 o = threefry2x32(0u, 42u, 0u, idx);
  const unsigned bits = o.x;
#else  // 4: partitionable, xor of both output words
  const uint2 o = threefry2x32(0u, 42u, 0u, idx);
  const unsigned bits = o.x ^ o.y;
#endif
  return (bits & 0x80000000u) ? 0.0f : 2.0f;  // keep -> /(1-p) = *2
}

__device__ __forceinline__ float lrelu(float v) {
  return v >= 0.0f ? v : 0.01f * v;
}

// C[M,128] = op(A) @ B  (+ fused epilogue).
// TRANS_A=false: A is [M,K] row-major (lda=K).
// TRANS_A=true : A is [K,M'] row-major (lda = M' = physical row length),
//                computing C[r,c] = sum_k A[k, rbase+r] * B[k,c]  (Ht^T case).
template <bool TRANS_A, int EPI>
__global__ __launch_bounds__(256) void gemm_kernel(
    const float* __restrict__ A, const float* __restrict__ B,
    float* __restrict__ C, int M, int K, int lda,
    const float* __restrict__ rowscale, const float* __restrict__ addmat,
    const float* __restrict__ bias, const float* __restrict__ fcw,
    const float* __restrict__ state, const float* __restrict__ fcb) {
  __shared__ float Ast[BK][AST];  // Ast[k][row]
  __shared__ float Bs[BK][BST];   // Bs[k][col]

  const int tid = threadIdx.x;
  const int rbase = blockIdx.x * BM;
  const int tx = tid & 31;  // col group: cols 4*tx..4*tx+3
  const int ty = tid >> 5;  // row group: rows 2*ty, 2*ty+1

  float acc[2][4] = {{0.f, 0.f, 0.f, 0.f}, {0.f, 0.f, 0.f, 0.f}};

  for (int k0 = 0; k0 < K; k0 += BK) {
    // ---- stage A tile (16 rows x 64 k) ----
    if (!TRANS_A) {
      const int row = tid >> 4;  // 0..15
      const int kp = tid & 15;   // 0..15 -> k offsets 4*kp..4*kp+3
      const float4 av =
          *(const float4*)(A + (size_t)(rbase + row) * lda + (k0 + 4 * kp));
      Ast[4 * kp + 0][row] = av.x;
      Ast[4 * kp + 1][row] = av.y;
      Ast[4 * kp + 2][row] = av.z;
      Ast[4 * kp + 3][row] = av.w;
    } else {
      const int e = tid >> 2;  // 0..63 (k within tile)
      const int p = tid & 3;   // 0..3  -> rows 4p..4p+3
      const float4 av =
          *(const float4*)(A + (size_t)(k0 + e) * lda + (rbase + 4 * p));
      *(float4*)&Ast[e][4 * p] = av;
    }
    // ---- stage B tile (64 k x 128 cols = 8192 floats; 256 thr * 8 * 4) ----
#pragma unroll
    for (int i = 0; i < 8; ++i) {
      const int k = (tid >> 5) + 8 * i;  // 0..63
      const int c = 4 * (tid & 31);      // 0..124
      *(float4*)&Bs[k][c] = *(const float4*)(B + (size_t)(k0 + k) * BN + c);
    }
    __syncthreads();
#pragma unroll 16
    for (int k = 0; k < BK; ++k) {
      const float2 a01 = *(const float2*)&Ast[k][2 * ty];
      const float4 b = *(const float4*)&Bs[k][4 * tx];
      acc[0][0] += a01.x * b.x;
      acc[0][1] += a01.x * b.y;
      acc[0][2] += a01.x * b.z;
      acc[0][3] += a01.x * b.w;
      acc[1][0] += a01.y * b.x;
      acc[1][1] += a01.y * b.y;
      acc[1][2] += a01.y * b.z;
      acc[1][3] += a01.y * b.w;
    }
    __syncthreads();
  }

  const int c0 = 4 * tx;
  const int r0 = rbase + 2 * ty;

  if (EPI == EPI_NONE) {
#pragma unroll
    for (int i = 0; i < 2; ++i) {
      *(float4*)(C + (size_t)(r0 + i) * BN + c0) =
          make_float4(acc[i][0], acc[i][1], acc[i][2], acc[i][3]);
    }
  } else if (EPI == EPI_ROWSCALE) {
#pragma unroll
    for (int i = 0; i < 2; ++i) {
      const float s = rowscale[r0 + i];
      *(float4*)(C + (size_t)(r0 + i) * BN + c0) =
          make_float4(acc[i][0] * s, acc[i][1] * s, acc[i][2] * s,
                      acc[i][3] * s);
    }
  } else if (EPI == EPI_LRELU_DROP) {
    const float4 bi = *(const float4*)(bias + c0);
#pragma unroll
    for (int i = 0; i < 2; ++i) {
      const int r = r0 + i;
      const float4 ad = *(const float4*)(addmat + (size_t)r * BN + c0);
      const unsigned fb = (unsigned)(r * BN + c0);
      const float v0 = lrelu(acc[i][0] + ad.x + bi.x) * drop_scale(fb + 0u);
      const float v1 = lrelu(acc[i][1] + ad.y + bi.y) * drop_scale(fb + 1u);
      const float v2 = lrelu(acc[i][2] + ad.z + bi.z) * drop_scale(fb + 2u);
      const float v3 = lrelu(acc[i][3] + ad.w + bi.w) * drop_scale(fb + 3u);
      *(float4*)(C + (size_t)r * BN + c0) = make_float4(v0, v1, v2, v3);
    }
  } else {  // EPI_LRELU2_FC: full row lives in this block -> reduce to out[r]
    const float4 bi = *(const float4*)(bias + c0);
    const float4 fw = *(const float4*)(fcw + c0);
#pragma unroll
    for (int i = 0; i < 2; ++i) {
      const int r = r0 + i;
      const float4 ad = *(const float4*)(addmat + (size_t)r * BN + c0);
      float p = lrelu(lrelu(acc[i][0] + ad.x + bi.x)) * fw.x +
                lrelu(lrelu(acc[i][1] + ad.y + bi.y)) * fw.y +
                lrelu(lrelu(acc[i][2] + ad.z + bi.z)) * fw.z +
                lrelu(lrelu(acc[i][3] + ad.w + bi.w)) * fw.w;
      // reduce over the 32 tx lanes (xor masks <=16 stay in the tx bits)
#pragma unroll
      for (int m = 16; m >= 1; m >>= 1) p += __shfl_xor(p, m, 64);
      if (tx == 0) C[r] = p + state[r] * fcw[128] + fcb[0];
    }
  }
}

extern "C" void kernel_launch(void* const* d_in, const int* in_sizes, int n_in,
                              void* d_out, int out_size, void* d_ws,
                              size_t ws_size, hipStream_t stream) {
  (void)in_sizes;
  (void)n_in;
  (void)out_size;
  (void)ws_size;

  const float* xi = (const float*)d_in[0];
  const float* x = (const float*)d_in[1];
  const float* Ht = (const float*)d_in[2];   // [E, N]
  const float* Hs = (const float*)d_in[3];   // [E, N]
  const float* state = (const float*)d_in[4];
  const float* wt0 = (const float*)d_in[5];
  const float* th0 = (const float*)d_in[6];
  const float* ew0 = (const float*)d_in[7];
  const float* bi0 = (const float*)d_in[8];
  const float* wt1 = (const float*)d_in[9];
  const float* th1 = (const float*)d_in[10];
  const float* ew1 = (const float*)d_in[11];
  const float* bi1 = (const float*)d_in[12];
  const float* fcw = (const float*)d_in[13];  // [129]
  const float* fcb = (const float*)d_in[14];  // [1]
  float* out = (float*)d_out;                 // [8192]

  constexpr int N = 8192, E = 4096, F = 128;

  // workspace layout (floats): T[N*F] | Badd[N*F] | Mb[E*F] | X1[N*F] = 14 MB
  float* ws = (float*)d_ws;
  float* T = ws;
  float* Badd = ws + (size_t)N * F;
  float* Mb = ws + 2 * (size_t)N * F;
  float* X1 = Mb + (size_t)E * F;

  const dim3 blk(256);

  // ---- hconv0 ----
  gemm_kernel<false, EPI_NONE><<<N / BM, blk, 0, stream>>>(
      x, th0, T, N, F, F, nullptr, nullptr, nullptr, nullptr, nullptr, nullptr);
  gemm_kernel<false, EPI_NONE><<<N / BM, blk, 0, stream>>>(
      xi, wt0, Badd, N, F, F, nullptr, nullptr, nullptr, nullptr, nullptr,
      nullptr);
  gemm_kernel<false, EPI_ROWSCALE><<<E / BM, blk, 0, stream>>>(
      Hs, T, Mb, E, N, N, ew0, nullptr, nullptr, nullptr, nullptr, nullptr);
  gemm_kernel<true, EPI_LRELU_DROP><<<N / BM, blk, 0, stream>>>(
      Ht, Mb, X1, N, E, N, nullptr, Badd, bi0, nullptr, nullptr, nullptr);

  // ---- hconv1 + head ----
  gemm_kernel<false, EPI_NONE><<<N / BM, blk, 0, stream>>>(
      X1, th1, T, N, F, F, nullptr, nullptr, nullptr, nullptr, nullptr,
      nullptr);
  gemm_kernel<false, EPI_NONE><<<N / BM, blk, 0, stream>>>(
      xi, wt1, Badd, N, F, F, nullptr, nullptr, nullptr, nullptr, nullptr,
      nullptr);
  gemm_kernel<false, EPI_ROWSCALE><<<E / BM, blk, 0, stream>>>(
      Hs, T, Mb, E, N, N, ew1, nullptr, nullptr, nullptr, nullptr, nullptr);
  gemm_kernel<true, EPI_LRELU2_FC><<<N / BM, blk, 0, stream>>>(
      Ht, Mb, out, N, E, N, nullptr, Badd, bi1, fcw, state, fcb);
}

// Round 4
// 521.683 us; speedup vs baseline: 3.0082x; 3.0082x over previous
//
#include <hip/hip_runtime.h>
#include <hip/hip_bf16.h>
#include <stdint.h>

// ---------------------------------------------------------------------------
// DQN hypergraph pipeline, round 4: bf16-MFMA with hi/lo split precision.
//
// Round-3 failed on precision only (absmax 2.62e6 vs 1.45e6 thr, 1.8x).
// Fix: represent activation operands as bf16 hi + bf16 lo (v ~ hi + lo,
// residual ~2^-17 rel) and accumulate A*Bh + A*Bl (big GEMMs; H stays
// plain bf16 -- its rounding error is sqrt(K)-attenuated vs the rank-one
// signal) and Ah*Bh + Ah*Bl + Al*Bh (small GEMMs).
// Everything else (threefry dropout, epilogues, split-K) unchanged from r3.
// ---------------------------------------------------------------------------

typedef short short8 __attribute__((ext_vector_type(8)));
typedef float f32x4 __attribute__((ext_vector_type(4)));

static constexpr int N = 8192, E = 4096, F = 128;
static constexpr int SA = 8, SB = 4;   // split-K factors (chunk = 1024 both)

__device__ __forceinline__ unsigned rotl32(unsigned x, int r) {
  return (x << r) | (x >> (32 - r));
}

__device__ __forceinline__ uint2 threefry2x32(unsigned k0, unsigned k1,
                                              unsigned x0, unsigned x1) {
  unsigned ks[3] = {k0, k1, k0 ^ k1 ^ 0x1BD11BDAu};
  x0 += ks[0];
  x1 += ks[1];
  const int R0[4] = {13, 15, 26, 6};
  const int R1[4] = {17, 29, 16, 24};
#pragma unroll
  for (int i = 0; i < 5; ++i) {
#pragma unroll
    for (int j = 0; j < 4; ++j) {
      const int r = (i % 2 == 0) ? R0[j] : R1[j];
      x0 += x1;
      x1 = rotl32(x1, r);
      x1 ^= x0;
    }
    x0 += ks[(i + 1) % 3];
    x1 += ks[(i + 2) % 3] + (unsigned)(i + 1);
  }
  return make_uint2(x0, x1);
}

// jax partitionable threefry bernoulli: bits = out.x ^ out.y, keep <=> MSB==0
__device__ __forceinline__ float drop_scale(unsigned idx) {
  const uint2 o = threefry2x32(0u, 42u, 0u, idx);
  return ((o.x ^ o.y) & 0x80000000u) ? 0.0f : 2.0f;
}

__device__ __forceinline__ float lrelu(float v) {
  return v >= 0.0f ? v : 0.01f * v;
}

__device__ __forceinline__ unsigned rne1(float a) {  // f32 -> bf16 (low 16)
  unsigned ua = __builtin_bit_cast(unsigned, a);
  ua += 0x7fffu + ((ua >> 16) & 1u);
  return ua >> 16;
}
__device__ __forceinline__ float bf16_val(unsigned u16) {
  return __builtin_bit_cast(float, u16 << 16);
}
__device__ __forceinline__ unsigned pk_bf16(float a, float b) {
  return rne1(a) | (rne1(b) << 16);
}
// hi/lo packed pair for (a,b)
__device__ __forceinline__ void split2(float a, float b, unsigned& hi,
                                       unsigned& lo) {
  const unsigned ha = rne1(a), hb = rne1(b);
  const float ra = a - bf16_val(ha), rb = b - bf16_val(hb);
  hi = ha | (hb << 16);
  lo = rne1(ra) | (rne1(rb) << 16);
}

// ---------------------------------------------------------------------------
// Big split-K GEMM, 128x128 tiles, BK=32, partials P[s][m][c] fp32.
// TRANSA=0: A fp32 [M][K] (Hs), lda=K. TRANSA=1: A fp32 [K][Mfull] (Ht), lda=N.
// Bt fp32 [128][K] k-contiguous; B operand staged as hi/lo.
// ---------------------------------------------------------------------------
template <bool TRANSA>
__global__ __launch_bounds__(256) void big_gemm(
    const float* __restrict__ A, const float* __restrict__ Bt,
    float* __restrict__ P, int M, int K, int lda, int kchunk) {
  __shared__ __align__(16) short As[128 * 40];
  __shared__ __align__(16) short Bh[128 * 40];
  __shared__ __align__(16) short Bl[128 * 40];

  const int tid = threadIdx.x;
  const int lane = tid & 63;
  const int w = tid >> 6;
  const int wm = (w & 1) << 6;
  const int wn = (w >> 1) << 6;
  const int l15 = lane & 15;
  const int koff = (lane >> 4) << 3;  // shorts

  const int r0 = blockIdx.x * 128;
  const int s = blockIdx.y;
  const int kbeg = s * kchunk;
  const int kend = kbeg + kchunk;

  f32x4 acc[4][4];
#pragma unroll
  for (int i = 0; i < 4; ++i)
#pragma unroll
    for (int j = 0; j < 4; ++j) acc[i][j] = (f32x4){0.f, 0.f, 0.f, 0.f};

  for (int k0 = kbeg; k0 < kend; k0 += 32) {
    // ---- stage A (128 m x 32 k, plain bf16) ----
    if (!TRANSA) {
#pragma unroll
      for (int i = 0; i < 4; ++i) {
        const int f = i * 256 + tid;  // 0..1023
        const int m = f >> 3;
        const int kq = f & 7;
        const float4 v =
            *(const float4*)(A + (size_t)(r0 + m) * lda + k0 + 4 * kq);
        uint2 u = {pk_bf16(v.x, v.y), pk_bf16(v.z, v.w)};
        *(uint2*)&As[m * 40 + 4 * kq] = u;
      }
    } else {
#pragma unroll
      for (int i = 0; i < 2; ++i) {
        const int f = i * 256 + tid;  // 0..511
        const int m = f & 127;
        const int eo = f >> 7;  // 0..3
        float vv[8];
#pragma unroll
        for (int r = 0; r < 8; ++r)
          vv[r] = A[(size_t)(k0 + 8 * eo + r) * lda + (r0 + m)];
        uint4 u = {pk_bf16(vv[0], vv[1]), pk_bf16(vv[2], vv[3]),
                   pk_bf16(vv[4], vv[5]), pk_bf16(vv[6], vv[7])};
        *(uint4*)&As[m * 40 + 8 * eo] = u;
      }
    }
    // ---- stage B (128 c x 32 k, hi/lo) ----
#pragma unroll
    for (int i = 0; i < 4; ++i) {
      const int q = i * 256 + tid;
      const int c = q >> 3;
      const int kq = q & 7;
      const float4 v = *(const float4*)(Bt + (size_t)c * K + k0 + 4 * kq);
      uint2 uh, ul;
      split2(v.x, v.y, uh.x, ul.x);
      split2(v.z, v.w, uh.y, ul.y);
      *(uint2*)&Bh[c * 40 + 4 * kq] = uh;
      *(uint2*)&Bl[c * 40 + 4 * kq] = ul;
    }
    __syncthreads();

    short8 af[4], bh[4], bl[4];
#pragma unroll
    for (int i = 0; i < 4; ++i)
      af[i] = *(const short8*)&As[(wm + 16 * i + l15) * 40 + koff];
#pragma unroll
    for (int j = 0; j < 4; ++j) {
      bh[j] = *(const short8*)&Bh[(wn + 16 * j + l15) * 40 + koff];
      bl[j] = *(const short8*)&Bl[(wn + 16 * j + l15) * 40 + koff];
    }
#pragma unroll
    for (int i = 0; i < 4; ++i)
#pragma unroll
      for (int j = 0; j < 4; ++j) {
        acc[i][j] = __builtin_amdgcn_mfma_f32_16x16x32_bf16(af[i], bl[j],
                                                            acc[i][j], 0, 0, 0);
        acc[i][j] = __builtin_amdgcn_mfma_f32_16x16x32_bf16(af[i], bh[j],
                                                            acc[i][j], 0, 0, 0);
      }
    __syncthreads();
  }

  const int rquad = (lane >> 4) << 2;
#pragma unroll
  for (int i = 0; i < 4; ++i)
#pragma unroll
    for (int j = 0; j < 4; ++j)
#pragma unroll
      for (int r = 0; r < 4; ++r) {
        const int row = r0 + wm + 16 * i + rquad + r;
        const int col = wn + 16 * j + l15;
        P[((size_t)s * M + row) * 128 + col] = acc[i][j][r];
      }
}

// ---------------------------------------------------------------------------
// Small GEMM vs 128x128 weight, K=128, BK=32 chunks, both operands hi/lo.
// WA=1: out = Tt[c][N] = (src @ W)^T. WA=0: out = Badd[n][128] = src @ W.
// ---------------------------------------------------------------------------
template <bool WA>
__global__ __launch_bounds__(256) void small_gemm(
    const float* __restrict__ src, const float* __restrict__ W,
    float* __restrict__ out) {
  __shared__ __align__(16) short WTh[128 * 40], WTl[128 * 40];
  __shared__ __align__(16) short Xh[64 * 40], Xl[64 * 40];

  const int tid = threadIdx.x;
  const int lane = tid & 63;
  const int w = tid >> 6;
  const int l15 = lane & 15;
  const int n0 = blockIdx.x * 64;

  constexpr int TI = WA ? 4 : 2;
  constexpr int TJ = WA ? 2 : 4;
  const int wm = (w & 1) * (WA ? 64 : 32);
  const int wn = (w >> 1) * (WA ? 32 : 64);

  f32x4 acc[TI][TJ];
#pragma unroll
  for (int i = 0; i < TI; ++i)
#pragma unroll
    for (int j = 0; j < TJ; ++j) acc[i][j] = (f32x4){0.f, 0.f, 0.f, 0.f};

  for (int k0 = 0; k0 < 128; k0 += 32) {
    // stage W chunk transposed: WT[c][k] = W[k0+k][c], hi/lo
#pragma unroll
    for (int i = 0; i < 2; ++i) {
      const int f = i * 256 + tid;  // 0..511
      const int c = f & 127;
      const int eo = f >> 7;  // 0..3
      uint4 uh, ul;
      unsigned* ph = (unsigned*)&uh;
      unsigned* pl = (unsigned*)&ul;
#pragma unroll
      for (int r = 0; r < 4; ++r) {
        const float a = W[(size_t)(k0 + 8 * eo + 2 * r) * 128 + c];
        const float b = W[(size_t)(k0 + 8 * eo + 2 * r + 1) * 128 + c];
        split2(a, b, ph[r], pl[r]);
      }
      *(uint4*)&WTh[c * 40 + 8 * eo] = uh;
      *(uint4*)&WTl[c * 40 + 8 * eo] = ul;
    }
    // stage src chunk: X[n][k], hi/lo
#pragma unroll
    for (int i = 0; i < 2; ++i) {
      const int q = i * 256 + tid;  // 0..511
      const int n = q >> 3;         // 0..63
      const int kq = q & 7;
      const float4 v = *(const float4*)(src + (size_t)(n0 + n) * 128 + k0 + 4 * kq);
      uint2 uh, ul;
      split2(v.x, v.y, uh.x, ul.x);
      split2(v.z, v.w, uh.y, ul.y);
      *(uint2*)&Xh[n * 40 + 4 * kq] = uh;
      *(uint2*)&Xl[n * 40 + 4 * kq] = ul;
    }
    __syncthreads();

    const int koff = (lane >> 4) << 3;
    short8 ah[TI], al[TI], bh[TJ], bl[TJ];
#pragma unroll
    for (int i = 0; i < TI; ++i) {
      const int m = wm + 16 * i + l15;
      ah[i] = WA ? *(const short8*)&WTh[m * 40 + koff]
                 : *(const short8*)&Xh[m * 40 + koff];
      al[i] = WA ? *(const short8*)&WTl[m * 40 + koff]
                 : *(const short8*)&Xl[m * 40 + koff];
    }
#pragma unroll
    for (int j = 0; j < TJ; ++j) {
      const int c = wn + 16 * j + l15;
      bh[j] = WA ? *(const short8*)&Xh[c * 40 + koff]
                 : *(const short8*)&WTh[c * 40 + koff];
      bl[j] = WA ? *(const short8*)&Xl[c * 40 + koff]
                 : *(const short8*)&WTl[c * 40 + koff];
    }
#pragma unroll
    for (int i = 0; i < TI; ++i)
#pragma unroll
      for (int j = 0; j < TJ; ++j) {
        acc[i][j] = __builtin_amdgcn_mfma_f32_16x16x32_bf16(al[i], bh[j],
                                                            acc[i][j], 0, 0, 0);
        acc[i][j] = __builtin_amdgcn_mfma_f32_16x16x32_bf16(ah[i], bl[j],
                                                            acc[i][j], 0, 0, 0);
        acc[i][j] = __builtin_amdgcn_mfma_f32_16x16x32_bf16(ah[i], bh[j],
                                                            acc[i][j], 0, 0, 0);
      }
    __syncthreads();
  }

  const int rquad = (lane >> 4) << 2;
#pragma unroll
  for (int i = 0; i < TI; ++i)
#pragma unroll
    for (int j = 0; j < TJ; ++j)
#pragma unroll
      for (int r = 0; r < 4; ++r) {
        const int row = wm + 16 * i + rquad + r;
        const int col = wn + 16 * j + l15;
        if (WA)  // Tt[c][n]
          out[(size_t)row * N + n0 + col] = acc[i][j][r];
        else  // Badd[n][c]
          out[(size_t)(n0 + row) * 128 + col] = acc[i][j][r];
      }
}

// Mt[c][e] = ew[e] * sum_s P[s][e][c];  P [SA][E][128]
__global__ __launch_bounds__(256) void reduce_A(const float* __restrict__ P,
                                                const float* __restrict__ ew,
                                                float* __restrict__ Mt) {
  __shared__ float Lt[32 * 132];
  const int tid = threadIdx.x;
  const int e0 = blockIdx.x * 32;
#pragma unroll
  for (int i = 0; i < 4; ++i) {
    const int f = i * 256 + tid;  // 0..1023
    const int el = f >> 5;
    const int cq = f & 31;
    float4 a = {0.f, 0.f, 0.f, 0.f};
#pragma unroll
    for (int s = 0; s < SA; ++s) {
      const float4 v =
          *(const float4*)(P + ((size_t)s * E + e0 + el) * 128 + 4 * cq);
      a.x += v.x; a.y += v.y; a.z += v.z; a.w += v.w;
    }
    const float sc = ew[e0 + el];
    a.x *= sc; a.y *= sc; a.z *= sc; a.w *= sc;
    *(float4*)&Lt[el * 132 + 4 * cq] = a;
  }
  __syncthreads();
#pragma unroll
  for (int i = 0; i < 4; ++i) {
    const int g = i * 256 + tid;  // 0..1023
    const int c = g >> 3;
    const int eq = g & 7;
    float4 o;
    o.x = Lt[(4 * eq + 0) * 132 + c];
    o.y = Lt[(4 * eq + 1) * 132 + c];
    o.z = Lt[(4 * eq + 2) * 132 + c];
    o.w = Lt[(4 * eq + 3) * 132 + c];
    *(float4*)&Mt[(size_t)c * E + e0 + 4 * eq] = o;
  }
}

// X1[n][c] = dropout(lrelu(sum_s P + Badd + bias));  P [SB][N][128]
__global__ __launch_bounds__(256) void reduce_B1(const float* __restrict__ P,
                                                 const float* __restrict__ Badd,
                                                 const float* __restrict__ bias,
                                                 float* __restrict__ X1) {
  const int q = blockIdx.x * 256 + threadIdx.x;
  const int n = q >> 5;
  const int cq = q & 31;
  float4 a = {0.f, 0.f, 0.f, 0.f};
#pragma unroll
  for (int s = 0; s < SB; ++s) {
    const float4 v = *(const float4*)(P + ((size_t)s * N + n) * 128 + 4 * cq);
    a.x += v.x; a.y += v.y; a.z += v.z; a.w += v.w;
  }
  const float4 b = *(const float4*)(Badd + (size_t)n * 128 + 4 * cq);
  const float4 bi = *(const float4*)(bias + 4 * cq);
  const unsigned fb = (unsigned)(n * 128 + 4 * cq);
  float4 o;
  o.x = lrelu(a.x + b.x + bi.x) * drop_scale(fb + 0u);
  o.y = lrelu(a.y + b.y + bi.y) * drop_scale(fb + 1u);
  o.z = lrelu(a.z + b.z + bi.z) * drop_scale(fb + 2u);
  o.w = lrelu(a.w + b.w + bi.w) * drop_scale(fb + 3u);
  *(float4*)&X1[(size_t)n * 128 + 4 * cq] = o;
}

// out[n] = sum_c lrelu(lrelu(sum_s P + Badd + bias)) * fcw[c]
//          + state[n]*fcw[128] + fcb[0]
__global__ __launch_bounds__(256) void reduce_B2(
    const float* __restrict__ P, const float* __restrict__ Badd,
    const float* __restrict__ bias, const float* __restrict__ fcw,
    const float* __restrict__ state, const float* __restrict__ fcb,
    float* __restrict__ out) {
  __shared__ float part[4];
  const int tid = threadIdx.x;
  const int nn = tid >> 7;
  const int c = tid & 127;
  const int n = blockIdx.x * 2 + nn;
  float v = 0.f;
#pragma unroll
  for (int s = 0; s < SB; ++s) v += P[((size_t)s * N + n) * 128 + c];
  v += Badd[(size_t)n * 128 + c] + bias[c];
  float p = lrelu(lrelu(v)) * fcw[c];
#pragma unroll
  for (int m = 32; m >= 1; m >>= 1) p += __shfl_xor(p, m, 64);
  if ((tid & 63) == 0) part[tid >> 6] = p;
  __syncthreads();
  if (tid < 2)
    out[blockIdx.x * 2 + tid] = part[2 * tid] + part[2 * tid + 1] +
                                state[blockIdx.x * 2 + tid] * fcw[128] + fcb[0];
}

extern "C" void kernel_launch(void* const* d_in, const int* in_sizes, int n_in,
                              void* d_out, int out_size, void* d_ws,
                              size_t ws_size, hipStream_t stream) {
  (void)in_sizes; (void)n_in; (void)out_size; (void)ws_size;

  const float* xi = (const float*)d_in[0];
  const float* x = (const float*)d_in[1];
  const float* Ht = (const float*)d_in[2];   // [E][N]
  const float* Hs = (const float*)d_in[3];   // [E][N]
  const float* state = (const float*)d_in[4];
  const float* wt0 = (const float*)d_in[5];
  const float* th0 = (const float*)d_in[6];
  const float* ew0 = (const float*)d_in[7];
  const float* bi0 = (const float*)d_in[8];
  const float* wt1 = (const float*)d_in[9];
  const float* th1 = (const float*)d_in[10];
  const float* ew1 = (const float*)d_in[11];
  const float* bi1 = (const float*)d_in[12];
  const float* fcw = (const float*)d_in[13];  // [129]
  const float* fcb = (const float*)d_in[14];  // [1]
  float* out = (float*)d_out;                 // [8192]

  // ws layout (floats): P[4M] | Tt[1M] | Badd[1M] | Mt[512K] | X1[1M] = 31.5MB
  float* ws = (float*)d_ws;
  float* P = ws;
  float* Tt = P + (size_t)4194304;
  float* Badd = Tt + (size_t)N * F;
  float* Mt = Badd + (size_t)N * F;
  float* X1 = Mt + (size_t)E * F;

  const dim3 blk(256);

  // ---- layer 1 ----
  small_gemm<true><<<N / 64, blk, 0, stream>>>(x, th0, Tt);
  small_gemm<false><<<N / 64, blk, 0, stream>>>(xi, wt0, Badd);
  big_gemm<false><<<dim3(E / 128, SA), blk, 0, stream>>>(Hs, Tt, P, E, N, N,
                                                         N / SA);
  reduce_A<<<E / 32, blk, 0, stream>>>(P, ew0, Mt);
  big_gemm<true><<<dim3(N / 128, SB), blk, 0, stream>>>(Ht, Mt, P, N, E, N,
                                                        E / SB);
  reduce_B1<<<N * F / 4 / 256, blk, 0, stream>>>(P, Badd, bi0, X1);

  // ---- layer 2 + head ----
  small_gemm<true><<<N / 64, blk, 0, stream>>>(X1, th1, Tt);
  small_gemm<false><<<N / 64, blk, 0, stream>>>(xi, wt1, Badd);
  big_gemm<false><<<dim3(E / 128, SA), blk, 0, stream>>>(Hs, Tt, P, E, N, N,
                                                         N / SA);
  reduce_A<<<E / 32, blk, 0, stream>>>(P, ew1, Mt);
  big_gemm<true><<<dim3(N / 128, SB), blk, 0, stream>>>(Ht, Mt, P, N, E, N,
                                                        E / SB);
  reduce_B2<<<N / 2, blk, 0, stream>>>(P, Badd, bi1, fcw, state, fcb, out);
}